// Round 2
// baseline (90.683 us; speedup 1.0000x reference)
//
#include <hip/hip_runtime.h>

#define T_SEQ 4096
#define NBATCH 2
#define DM 1024
#define DI 32
#define NH 4
#define NCOLS 164      // 128 q + 32 k + 4 w
#define NCOLS_PAD 176  // 11 tiles of 16

typedef __attribute__((ext_vector_type(8))) short bf16x8;
typedef __attribute__((ext_vector_type(4))) float f32x4;

__device__ __forceinline__ unsigned short f2bf(float f) {
    unsigned int u = __builtin_bit_cast(unsigned int, f);
    u += 0x7FFFu + ((u >> 16) & 1u);   // RNE; inputs have no NaN
    return (unsigned short)(u >> 16);
}

// ---------------- prep: W^T -> bf16 [176][1024], bias[176] ----------------
__global__ __launch_bounds__(256) void prep_kernel(
    const float* __restrict__ Wq, const float* __restrict__ bq,
    const float* __restrict__ Wk, const float* __restrict__ bk,
    const float* __restrict__ Ww, const float* __restrict__ bw,
    unsigned short* __restrict__ WT, float* __restrict__ bias) {
    int c = blockIdx.x;                    // 0..175
    const float* src = nullptr; int stride = 0; float bv = 0.f;
    if (c < 128)      { src = Wq + c;       stride = NH * DI; bv = bq[c]; }
    else if (c < 160) { src = Wk + (c-128); stride = DI;      bv = bk[c-128]; }
    else if (c < 164) { src = Ww + (c-160); stride = NH;      bv = bw[c-160]; }
    for (int k = threadIdx.x; k < DM; k += blockDim.x) {
        float v = src ? src[(size_t)k * stride] : 0.f;
        WT[(size_t)c * DM + k] = f2bf(v);
    }
    if (threadIdx.x == 0) bias[c] = bv;
}

// ---------------- projection: [8192 x 176] = x[8192 x 1024] * W ----------------
// block = one 16-row tile; 4 waves split the 11 col-tiles (3/3/3/2).
// 512 blocks -> 2 blocks/CU -> 8 waves/CU for latency hiding; the 4 waves
// re-read the same 16 x-rows (L1/L2-served, HBM traffic unchanged).
__global__ __launch_bounds__(256) void proj_kernel(
    const float* __restrict__ x, const unsigned short* __restrict__ WT,
    const float* __restrict__ bias,
    unsigned short* __restrict__ qws, unsigned short* __restrict__ kws,
    float* __restrict__ wws) {
    int wave = threadIdx.x >> 6;
    int lane = threadIdx.x & 63;
    int rowTile = blockIdx.x;              // 0..511
    int ct0 = wave * 3;
    int nct = (wave < 3) ? 3 : 2;          // tiles 0..10
    int lr = lane & 15, kg = lane >> 4;
    int r0 = rowTile * 16;

    // A-fragment source row (row index r = b*T + t; x is [T][B][D])
    int rowA = r0 + lr;
    int tA = rowA & (T_SEQ - 1), bA = rowA >> 12;
    const float* xrow = x + ((size_t)tA * NBATCH + bA) * DM;

    f32x4 acc[3] = {};
    #pragma unroll 2
    for (int k0 = 0; k0 < DM; k0 += 32) {
        const float* xp = xrow + k0 + kg * 8;
        f32x4 a0 = *(const f32x4*)xp;
        f32x4 a1 = *(const f32x4*)(xp + 4);
        bf16x8 af;
        af[0] = (short)f2bf(a0[0]); af[1] = (short)f2bf(a0[1]);
        af[2] = (short)f2bf(a0[2]); af[3] = (short)f2bf(a0[3]);
        af[4] = (short)f2bf(a1[0]); af[5] = (short)f2bf(a1[1]);
        af[6] = (short)f2bf(a1[2]); af[7] = (short)f2bf(a1[3]);
        #pragma unroll
        for (int i = 0; i < 3; ++i) {
            if (i < nct) {   // wave-uniform
                int c = (ct0 + i) * 16 + lr;
                bf16x8 bfg = *(const bf16x8*)(WT + (size_t)c * DM + k0 + kg * 8);
                acc[i] = __builtin_amdgcn_mfma_f32_16x16x32_bf16(af, bfg, acc[i], 0, 0, 0);
            }
        }
    }
    // epilogue: D col = lane&15, row = (lane>>4)*4 + reg
    #pragma unroll
    for (int i = 0; i < 3; ++i) {
        if (i < nct) {
            int cout = (ct0 + i) * 16 + lr;
            float bv = bias[cout];
            #pragma unroll
            for (int r = 0; r < 4; ++r) {
                int rr = r0 + kg * 4 + r;
                int tt = rr & (T_SEQ - 1), bb = rr >> 12;
                float v = acc[i][r] + bv;
                size_t rowoff = (size_t)bb * T_SEQ + tt;
                if (cout < 128)       qws[rowoff * 128 + cout] = f2bf(v);
                else if (cout < 160)  kws[rowoff * 32 + (cout - 128)] = f2bf(v);
                else if (cout < 164)  wws[rowoff * 4 + (cout - 160)] = v;
            }
        }
    }
}

// ---------------- main: out[b][t][s] = sum_h relu(q_h . k) * w_h ----------------
// Swapped operands: mfma(A=k, B=q) -> D[row=s_local, col=t_local].
// Lane (kg,lr) holds 4 consecutive s at one t-row -> dwordx4 stores.
__global__ __launch_bounds__(256) void indexer_kernel(
    const unsigned short* __restrict__ qws, const unsigned short* __restrict__ kws,
    const float* __restrict__ wws, float* __restrict__ out) {
    int wave = threadIdx.x >> 6;
    int lane = threadIdx.x & 63;
    int gw = blockIdx.x * 4 + wave;        // 0..8191
    int strip = gw & 15;
    int t16 = (gw >> 4) & 255;
    int b = gw >> 12;
    int t0 = t16 * 16;
    int lr = lane & 15, kg = lane >> 4;

    // B fragments: 4 heads of q (B col = lane%16 = t_local, k at kg*8..+8)
    const unsigned short* qrow = qws + ((size_t)b * T_SEQ + t0 + lr) * 128;
    bf16x8 qf[4];
    #pragma unroll
    for (int h = 0; h < 4; ++h)
        qf[h] = *(const bf16x8*)(qrow + h * 32 + kg * 8);

    // head weights for this lane's t-row (t = t0 + lr)
    f32x4 w4 = *(const f32x4*)(wws + ((size_t)b * T_SEQ + t0 + lr) * 4);

    float* outrow = out + (size_t)b * T_SEQ * T_SEQ + (size_t)(t0 + lr) * T_SEQ;
    const unsigned short* kbase = kws + (size_t)b * T_SEQ * 32;
    int sbase = strip * 256;

    for (int st = 0; st < 16; ++st) {
        int s0 = sbase + st * 16;
        // A fragment: k rows = s (A row = lane%16), k at kg*8..+8
        bf16x8 kf = *(const bf16x8*)(kbase + (size_t)(s0 + lr) * 32 + kg * 8);
        f32x4 z = {0.f, 0.f, 0.f, 0.f};
        f32x4 a0 = __builtin_amdgcn_mfma_f32_16x16x32_bf16(kf, qf[0], z, 0, 0, 0);
        f32x4 a1 = __builtin_amdgcn_mfma_f32_16x16x32_bf16(kf, qf[1], z, 0, 0, 0);
        f32x4 a2 = __builtin_amdgcn_mfma_f32_16x16x32_bf16(kf, qf[2], z, 0, 0, 0);
        f32x4 a3 = __builtin_amdgcn_mfma_f32_16x16x32_bf16(kf, qf[3], z, 0, 0, 0);
        f32x4 v;
        #pragma unroll
        for (int r = 0; r < 4; ++r) {
            v[r] = fmaxf(a0[r], 0.f) * w4[0] + fmaxf(a1[r], 0.f) * w4[1]
                 + fmaxf(a2[r], 0.f) * w4[2] + fmaxf(a3[r], 0.f) * w4[3];
        }
        // store 4 consecutive s of row t0+lr: 16 B/lane, 64 B contiguous per row
        __builtin_nontemporal_store(v, (f32x4*)(outrow + s0 + kg * 4));
    }
}

extern "C" void kernel_launch(void* const* d_in, const int* in_sizes, int n_in,
                              void* d_out, int out_size, void* d_ws, size_t ws_size,
                              hipStream_t stream) {
    const float* x  = (const float*)d_in[0];
    const float* Wq = (const float*)d_in[1];
    const float* bq = (const float*)d_in[2];
    const float* Wk = (const float*)d_in[3];
    const float* bk = (const float*)d_in[4];
    const float* Ww = (const float*)d_in[5];
    const float* bw = (const float*)d_in[6];
    float* out = (float*)d_out;

    char* ws = (char*)d_ws;
    unsigned short* WT  = (unsigned short*)(ws);            // 176*1024*2 = 360448 B
    float* bias         = (float*)(ws + 360448);            // 704 B
    unsigned short* qws = (unsigned short*)(ws + 524288);   // 2*4096*128*2 = 2 MB
    unsigned short* kws = (unsigned short*)(ws + 2621440);  // 2*4096*32*2 = 512 KB
    float* wws          = (float*)(ws + 3145728);           // 2*4096*4*4 = 128 KB

    prep_kernel<<<dim3(NCOLS_PAD), dim3(256), 0, stream>>>(Wq, bq, Wk, bk, Ww, bw, WT, bias);
    proj_kernel<<<dim3(512), dim3(256), 0, stream>>>(x, WT, bias, qws, kws, wws);
    indexer_kernel<<<dim3(2048), dim3(256), 0, stream>>>(qws, kws, wws, out);
}

// Round 3
// 77.566 us; speedup vs baseline: 1.1691x; 1.1691x over previous
//
#include <hip/hip_runtime.h>

#define T_SEQ 4096
#define NBATCH 2
#define DM 1024
#define DI 32
#define NH 4
#define NCOLS 164      // 128 q + 32 k + 4 w
#define NCOLS_PAD 176  // 11 tiles of 16

typedef __attribute__((ext_vector_type(8))) short bf16x8;
typedef __attribute__((ext_vector_type(4))) float f32x4;

__device__ __forceinline__ unsigned short f2bf(float f) {
    unsigned int u = __builtin_bit_cast(unsigned int, f);
    u += 0x7FFFu + ((u >> 16) & 1u);   // RNE; inputs have no NaN
    return (unsigned short)(u >> 16);
}

// ---------------- prep: W^T -> bf16 [176][1024], bias[176] ----------------
__global__ __launch_bounds__(256) void prep_kernel(
    const float* __restrict__ Wq, const float* __restrict__ bq,
    const float* __restrict__ Wk, const float* __restrict__ bk,
    const float* __restrict__ Ww, const float* __restrict__ bw,
    unsigned short* __restrict__ WT, float* __restrict__ bias) {
    int c = blockIdx.x;                    // 0..175
    const float* src = nullptr; int stride = 0; float bv = 0.f;
    if (c < 128)      { src = Wq + c;       stride = NH * DI; bv = bq[c]; }
    else if (c < 160) { src = Wk + (c-128); stride = DI;      bv = bk[c-128]; }
    else if (c < 164) { src = Ww + (c-160); stride = NH;      bv = bw[c-160]; }
    for (int k = threadIdx.x; k < DM; k += blockDim.x) {
        float v = src ? src[(size_t)k * stride] : 0.f;
        WT[(size_t)c * DM + k] = f2bf(v);
    }
    if (threadIdx.x == 0) bias[c] = bv;
}

// ---------------- projection: [8192 x 176] = x[8192 x 1024] * W ----------------
// R1 structure: one wave = one 16-row tile, owns 6 (or 5) col-tiles; K loop 1024/32
__global__ __launch_bounds__(256) void proj_kernel(
    const float* __restrict__ x, const unsigned short* __restrict__ WT,
    const float* __restrict__ bias,
    unsigned short* __restrict__ qws, unsigned short* __restrict__ kws,
    float* __restrict__ wws) {
    int wave = threadIdx.x >> 6;
    int lane = threadIdx.x & 63;
    int gw = blockIdx.x * 4 + wave;        // 0..1023
    int rowTile = gw >> 1;                 // 0..511
    int half = gw & 1;
    int ct0 = half ? 6 : 0;
    int nct = half ? 5 : 6;
    int lr = lane & 15, kg = lane >> 4;
    int r0 = rowTile * 16;

    // A-fragment source row (row index r = b*T + t; x is [T][B][D])
    int rowA = r0 + lr;
    int tA = rowA & (T_SEQ - 1), bA = rowA >> 12;
    const float* xrow = x + ((size_t)tA * NBATCH + bA) * DM;

    f32x4 acc[6] = {};
    for (int k0 = 0; k0 < DM; k0 += 32) {
        const float* xp = xrow + k0 + kg * 8;
        f32x4 a0 = *(const f32x4*)xp;
        f32x4 a1 = *(const f32x4*)(xp + 4);
        bf16x8 af;
        af[0] = (short)f2bf(a0[0]); af[1] = (short)f2bf(a0[1]);
        af[2] = (short)f2bf(a0[2]); af[3] = (short)f2bf(a0[3]);
        af[4] = (short)f2bf(a1[0]); af[5] = (short)f2bf(a1[1]);
        af[6] = (short)f2bf(a1[2]); af[7] = (short)f2bf(a1[3]);
        #pragma unroll
        for (int i = 0; i < 6; ++i) {
            if (i < nct) {   // wave-uniform
                int c = (ct0 + i) * 16 + lr;
                bf16x8 bfg = *(const bf16x8*)(WT + (size_t)c * DM + k0 + kg * 8);
                acc[i] = __builtin_amdgcn_mfma_f32_16x16x32_bf16(af, bfg, acc[i], 0, 0, 0);
            }
        }
    }
    // epilogue: D col = lane&15, row = (lane>>4)*4 + reg
    #pragma unroll
    for (int i = 0; i < 6; ++i) {
        if (i < nct) {
            int cout = (ct0 + i) * 16 + lr;
            float bv = bias[cout];
            #pragma unroll
            for (int r = 0; r < 4; ++r) {
                int rr = r0 + kg * 4 + r;
                int tt = rr & (T_SEQ - 1), bb = rr >> 12;
                float v = acc[i][r] + bv;
                size_t rowoff = (size_t)bb * T_SEQ + tt;
                if (cout < 128)       qws[rowoff * 128 + cout] = f2bf(v);
                else if (cout < 160)  kws[rowoff * 32 + (cout - 128)] = f2bf(v);
                else if (cout < 164)  wws[rowoff * 4 + (cout - 160)] = v;
            }
        }
    }
}

// ---------------- main: out[b][t][s] = sum_h relu(q_h . k) * w_h ----------------
// Swapped operands: mfma(A=k, B=q) -> D[row=s_local, col=t_local].
// Process 4 adjacent s-tiles per group; issue the 4 row-adjacent dwordx4
// stores back-to-back so L2 write-combines 256 B/row immediately.
__global__ __launch_bounds__(256) void indexer_kernel(
    const unsigned short* __restrict__ qws, const unsigned short* __restrict__ kws,
    const float* __restrict__ wws, float* __restrict__ out) {
    int wave = threadIdx.x >> 6;
    int lane = threadIdx.x & 63;
    int gw = blockIdx.x * 4 + wave;        // 0..8191
    int strip = gw & 15;
    int t16 = (gw >> 4) & 255;
    int b = gw >> 12;
    int t0 = t16 * 16;
    int lr = lane & 15, kg = lane >> 4;

    // B fragments: 4 heads of q (B col = lane%16 = t_local, k at kg*8..+8)
    const unsigned short* qrow = qws + ((size_t)b * T_SEQ + t0 + lr) * 128;
    bf16x8 qf[4];
    #pragma unroll
    for (int h = 0; h < 4; ++h)
        qf[h] = *(const bf16x8*)(qrow + h * 32 + kg * 8);

    // head weights for this lane's t-row (t = t0 + lr)
    f32x4 w4 = *(const f32x4*)(wws + ((size_t)b * T_SEQ + t0 + lr) * 4);

    float* outrow = out + (size_t)b * T_SEQ * T_SEQ + (size_t)(t0 + lr) * T_SEQ;
    const unsigned short* kbase = kws + (size_t)b * T_SEQ * 32;
    int sbase = strip * 256;

    for (int g = 0; g < 4; ++g) {
        int s0 = sbase + g * 64;
        // batch the 4 independent k-fragment loads (A row = lane%16 = s_local)
        bf16x8 kf0 = *(const bf16x8*)(kbase + (size_t)(s0      + lr) * 32 + kg * 8);
        bf16x8 kf1 = *(const bf16x8*)(kbase + (size_t)(s0 + 16 + lr) * 32 + kg * 8);
        bf16x8 kf2 = *(const bf16x8*)(kbase + (size_t)(s0 + 32 + lr) * 32 + kg * 8);
        bf16x8 kf3 = *(const bf16x8*)(kbase + (size_t)(s0 + 48 + lr) * 32 + kg * 8);
        f32x4 z = {0.f, 0.f, 0.f, 0.f};
        f32x4 v[4];
        #pragma unroll
        for (int j = 0; j < 4; ++j) {
            bf16x8 kf = (j == 0) ? kf0 : (j == 1) ? kf1 : (j == 2) ? kf2 : kf3;
            f32x4 a0 = __builtin_amdgcn_mfma_f32_16x16x32_bf16(kf, qf[0], z, 0, 0, 0);
            f32x4 a1 = __builtin_amdgcn_mfma_f32_16x16x32_bf16(kf, qf[1], z, 0, 0, 0);
            f32x4 a2 = __builtin_amdgcn_mfma_f32_16x16x32_bf16(kf, qf[2], z, 0, 0, 0);
            f32x4 a3 = __builtin_amdgcn_mfma_f32_16x16x32_bf16(kf, qf[3], z, 0, 0, 0);
            #pragma unroll
            for (int r = 0; r < 4; ++r) {
                v[j][r] = fmaxf(a0[r], 0.f) * w4[0] + fmaxf(a1[r], 0.f) * w4[1]
                        + fmaxf(a2[r], 0.f) * w4[2] + fmaxf(a3[r], 0.f) * w4[3];
            }
        }
        // 4 back-to-back stores: per row t0+lr, 256 B contiguous (4 x 64 B)
        #pragma unroll
        for (int j = 0; j < 4; ++j)
            *(f32x4*)(outrow + s0 + j * 16 + kg * 4) = v[j];
    }
}

extern "C" void kernel_launch(void* const* d_in, const int* in_sizes, int n_in,
                              void* d_out, int out_size, void* d_ws, size_t ws_size,
                              hipStream_t stream) {
    const float* x  = (const float*)d_in[0];
    const float* Wq = (const float*)d_in[1];
    const float* bq = (const float*)d_in[2];
    const float* Wk = (const float*)d_in[3];
    const float* bk = (const float*)d_in[4];
    const float* Ww = (const float*)d_in[5];
    const float* bw = (const float*)d_in[6];
    float* out = (float*)d_out;

    char* ws = (char*)d_ws;
    unsigned short* WT  = (unsigned short*)(ws);            // 176*1024*2 = 360448 B
    float* bias         = (float*)(ws + 360448);            // 704 B
    unsigned short* qws = (unsigned short*)(ws + 524288);   // 2*4096*128*2 = 2 MB
    unsigned short* kws = (unsigned short*)(ws + 2621440);  // 2*4096*32*2 = 512 KB
    float* wws          = (float*)(ws + 3145728);           // 2*4096*4*4 = 128 KB

    prep_kernel<<<dim3(NCOLS_PAD), dim3(256), 0, stream>>>(Wq, bq, Wk, bk, Ww, bw, WT, bias);
    proj_kernel<<<dim3(256), dim3(256), 0, stream>>>(x, WT, bias, qws, kws, wws);
    indexer_kernel<<<dim3(2048), dim3(256), 0, stream>>>(qws, kws, wws, out);
}

// Round 4
// 71.862 us; speedup vs baseline: 1.2619x; 1.0794x over previous
//
#include <hip/hip_runtime.h>

#define T_SEQ 4096
#define NBATCH 2
#define DM 1024
#define DI 32
#define NH 4
#define NCOLS 164      // 128 q + 32 k + 4 w
#define NCOLS_PAD 192  // 12 tiles of 16 (pad cols 164..191 = zeros -> branch-free K-loop)

typedef __attribute__((ext_vector_type(8))) short bf16x8;
typedef __attribute__((ext_vector_type(4))) float f32x4;

__device__ __forceinline__ unsigned short f2bf(float f) {
    unsigned int u = __builtin_bit_cast(unsigned int, f);
    u += 0x7FFFu + ((u >> 16) & 1u);   // RNE; inputs have no NaN
    return (unsigned short)(u >> 16);
}

// ---------------- prep: W^T -> bf16 [192][1024], bias[192] ----------------
__global__ __launch_bounds__(256) void prep_kernel(
    const float* __restrict__ Wq, const float* __restrict__ bq,
    const float* __restrict__ Wk, const float* __restrict__ bk,
    const float* __restrict__ Ww, const float* __restrict__ bw,
    unsigned short* __restrict__ WT, float* __restrict__ bias) {
    int c = blockIdx.x;                    // 0..191
    const float* src = nullptr; int stride = 0; float bv = 0.f;
    if (c < 128)      { src = Wq + c;       stride = NH * DI; bv = bq[c]; }
    else if (c < 160) { src = Wk + (c-128); stride = DI;      bv = bk[c-128]; }
    else if (c < 164) { src = Ww + (c-160); stride = NH;      bv = bw[c-160]; }
    for (int k = threadIdx.x; k < DM; k += blockDim.x) {
        float v = src ? src[(size_t)k * stride] : 0.f;
        WT[(size_t)c * DM + k] = f2bf(v);
    }
    if (threadIdx.x == 0) bias[c] = bv;
}

// ---------------- projection: [8192 x 192] = x[8192 x 1024] * W ----------------
// Block = one 16-row tile. Stage 16 x-rows ONCE into LDS (fragment-major bf16),
// then 4 waves each own 3 col-tiles; K-loop is branch-free:
// 1 linear ds_read_b128 (A) + 3 L2 B-loads + 3 MFMA per iteration.
__global__ __launch_bounds__(256) void proj_kernel(
    const float* __restrict__ x, const unsigned short* __restrict__ WT,
    const float* __restrict__ bias,
    unsigned short* __restrict__ qws, unsigned short* __restrict__ kws,
    float* __restrict__ wws) {
    __shared__ unsigned short afrag[32 * 512];   // 32 k-chunks x (64 lanes x 8 bf16) = 32 KB
    int wave = threadIdx.x >> 6;
    int lane = threadIdx.x & 63;
    int lr = lane & 15, kg = lane >> 4;
    int r0 = blockIdx.x * 16;

    // A source row (row index r = b*T + t; x is [T][B][D])
    int rowA = r0 + lr;
    int tA = rowA & (T_SEQ - 1), bA = rowA >> 12;
    const float* xrow = x + ((size_t)tA * NBATCH + bA) * DM;

    // stage: wave w covers k-chunks c = w*8 .. w*8+7.
    // Per chunk: wave reads 16 rows x 128 B (full contiguous lines), writes
    // the MFMA A-fragment linearly at [c*512 + lane*8] bf16.
    #pragma unroll
    for (int j = 0; j < 8; ++j) {
        int c = wave * 8 + j;
        const float* xp = xrow + c * 32 + kg * 8;
        f32x4 a0 = *(const f32x4*)xp;
        f32x4 a1 = *(const f32x4*)(xp + 4);
        bf16x8 af;
        af[0] = (short)f2bf(a0[0]); af[1] = (short)f2bf(a0[1]);
        af[2] = (short)f2bf(a0[2]); af[3] = (short)f2bf(a0[3]);
        af[4] = (short)f2bf(a1[0]); af[5] = (short)f2bf(a1[1]);
        af[6] = (short)f2bf(a1[2]); af[7] = (short)f2bf(a1[3]);
        *(bf16x8*)(&afrag[c * 512 + lane * 8]) = af;
    }
    __syncthreads();

    int ct0 = wave * 3;                    // tiles 0..11, 3 per wave, no branches
    f32x4 acc[3] = {};
    #pragma unroll 2
    for (int c = 0; c < 32; ++c) {
        bf16x8 af = *(const bf16x8*)(&afrag[c * 512 + lane * 8]);
        int k0 = c * 32;
        #pragma unroll
        for (int i = 0; i < 3; ++i) {
            int col = (ct0 + i) * 16 + lr;
            bf16x8 bfg = *(const bf16x8*)(WT + (size_t)col * DM + k0 + kg * 8);
            acc[i] = __builtin_amdgcn_mfma_f32_16x16x32_bf16(af, bfg, acc[i], 0, 0, 0);
        }
    }

    // epilogue: D col = lane&15, row = (lane>>4)*4 + reg
    #pragma unroll
    for (int i = 0; i < 3; ++i) {
        int cout = (ct0 + i) * 16 + lr;
        float bv = bias[cout];
        #pragma unroll
        for (int r = 0; r < 4; ++r) {
            int rr = r0 + kg * 4 + r;
            int tt = rr & (T_SEQ - 1), bb = rr >> 12;
            float v = acc[i][r] + bv;
            size_t rowoff = (size_t)bb * T_SEQ + tt;
            if (cout < 128)       qws[rowoff * 128 + cout] = f2bf(v);
            else if (cout < 160)  kws[rowoff * 32 + (cout - 128)] = f2bf(v);
            else if (cout < 164)  wws[rowoff * 4 + (cout - 160)] = v;
        }
    }
}

// ---------------- main: out[b][t][s] = sum_h relu(q_h . k) * w_h ----------------
// (bit-identical to R3 — control for this round's proj experiment)
__global__ __launch_bounds__(256) void indexer_kernel(
    const unsigned short* __restrict__ qws, const unsigned short* __restrict__ kws,
    const float* __restrict__ wws, float* __restrict__ out) {
    int wave = threadIdx.x >> 6;
    int lane = threadIdx.x & 63;
    int gw = blockIdx.x * 4 + wave;        // 0..8191
    int strip = gw & 15;
    int t16 = (gw >> 4) & 255;
    int b = gw >> 12;
    int t0 = t16 * 16;
    int lr = lane & 15, kg = lane >> 4;

    const unsigned short* qrow = qws + ((size_t)b * T_SEQ + t0 + lr) * 128;
    bf16x8 qf[4];
    #pragma unroll
    for (int h = 0; h < 4; ++h)
        qf[h] = *(const bf16x8*)(qrow + h * 32 + kg * 8);

    f32x4 w4 = *(const f32x4*)(wws + ((size_t)b * T_SEQ + t0 + lr) * 4);

    float* outrow = out + (size_t)b * T_SEQ * T_SEQ + (size_t)(t0 + lr) * T_SEQ;
    const unsigned short* kbase = kws + (size_t)b * T_SEQ * 32;
    int sbase = strip * 256;

    for (int g = 0; g < 4; ++g) {
        int s0 = sbase + g * 64;
        bf16x8 kf0 = *(const bf16x8*)(kbase + (size_t)(s0      + lr) * 32 + kg * 8);
        bf16x8 kf1 = *(const bf16x8*)(kbase + (size_t)(s0 + 16 + lr) * 32 + kg * 8);
        bf16x8 kf2 = *(const bf16x8*)(kbase + (size_t)(s0 + 32 + lr) * 32 + kg * 8);
        bf16x8 kf3 = *(const bf16x8*)(kbase + (size_t)(s0 + 48 + lr) * 32 + kg * 8);
        f32x4 z = {0.f, 0.f, 0.f, 0.f};
        f32x4 v[4];
        #pragma unroll
        for (int j = 0; j < 4; ++j) {
            bf16x8 kf = (j == 0) ? kf0 : (j == 1) ? kf1 : (j == 2) ? kf2 : kf3;
            f32x4 a0 = __builtin_amdgcn_mfma_f32_16x16x32_bf16(kf, qf[0], z, 0, 0, 0);
            f32x4 a1 = __builtin_amdgcn_mfma_f32_16x16x32_bf16(kf, qf[1], z, 0, 0, 0);
            f32x4 a2 = __builtin_amdgcn_mfma_f32_16x16x32_bf16(kf, qf[2], z, 0, 0, 0);
            f32x4 a3 = __builtin_amdgcn_mfma_f32_16x16x32_bf16(kf, qf[3], z, 0, 0, 0);
            #pragma unroll
            for (int r = 0; r < 4; ++r) {
                v[j][r] = fmaxf(a0[r], 0.f) * w4[0] + fmaxf(a1[r], 0.f) * w4[1]
                        + fmaxf(a2[r], 0.f) * w4[2] + fmaxf(a3[r], 0.f) * w4[3];
            }
        }
        #pragma unroll
        for (int j = 0; j < 4; ++j)
            *(f32x4*)(outrow + s0 + j * 16 + kg * 4) = v[j];
    }
}

extern "C" void kernel_launch(void* const* d_in, const int* in_sizes, int n_in,
                              void* d_out, int out_size, void* d_ws, size_t ws_size,
                              hipStream_t stream) {
    const float* x  = (const float*)d_in[0];
    const float* Wq = (const float*)d_in[1];
    const float* bq = (const float*)d_in[2];
    const float* Wk = (const float*)d_in[3];
    const float* bk = (const float*)d_in[4];
    const float* Ww = (const float*)d_in[5];
    const float* bw = (const float*)d_in[6];
    float* out = (float*)d_out;

    char* ws = (char*)d_ws;
    unsigned short* WT  = (unsigned short*)(ws);            // 192*1024*2 = 393216 B
    float* bias         = (float*)(ws + 393216);            // 768 B
    unsigned short* qws = (unsigned short*)(ws + 524288);   // 2*4096*128*2 = 2 MB
    unsigned short* kws = (unsigned short*)(ws + 2621440);  // 2*4096*32*2 = 512 KB
    float* wws          = (float*)(ws + 3145728);           // 2*4096*4*4 = 128 KB

    prep_kernel<<<dim3(NCOLS_PAD), dim3(256), 0, stream>>>(Wq, bq, Wk, bk, Ww, bw, WT, bias);
    proj_kernel<<<dim3(512), dim3(256), 0, stream>>>(x, WT, bias, qws, kws, wws);
    indexer_kernel<<<dim3(2048), dim3(256), 0, stream>>>(qws, kws, wws, out);
}